// Round 7
// baseline (404.481 us; speedup 1.0000x reference)
//
#include <hip/hip_runtime.h>
#include <stdint.h>

#define B_DIM 4096
#define IN_SZ 1024
#define HID   2048
#define D_DIM 3072   // K = IN_SZ + HID
#define BM 256       // batch rows per block
#define BN 64        // h-columns per block (x4 gates = 256 logical cols)
#define BK2 128      // K-elems per tile iteration (4 k-slices of 32)
#define NT2 (D_DIM / BK2)   // 24

typedef float  f32x4  __attribute__((ext_vector_type(4)));
typedef short  short8 __attribute__((ext_vector_type(8)));

__device__ __forceinline__ unsigned short f2bf(float f) {
    union { float f; unsigned u; } v; v.f = f;
    unsigned u = v.u + 0x7fffu + ((v.u >> 16) & 1u);   // RNE
    return (unsigned short)(u >> 16);
}

__device__ __forceinline__ void async_load16(const void* g, void* l) {
    __builtin_amdgcn_global_load_lds(
        (const __attribute__((address_space(1))) unsigned int*)g,
        (__attribute__((address_space(3))) unsigned int*)l,
        16, 0, 0);
}

__device__ __forceinline__ float sigm(float x) {
    return 1.0f / (1.0f + __expf(-x));
}
__device__ __forceinline__ float tanh_f(float x) {
    return 1.0f - 2.0f / (__expf(2.0f * x) + 1.0f);
}

// ---- single prepass (grid-stride): concat(x,h)->bf16 [B][D], concat(W)->bf16 [4H][D] ----
__global__ __launch_bounds__(256)
void convert_all(const float* __restrict__ x, const float* __restrict__ h,
                 const float* __restrict__ W0, const float* __restrict__ W1,
                 const float* __restrict__ W2, const float* __restrict__ W3,
                 unsigned short* __restrict__ Abf, unsigned short* __restrict__ Wbf) {
    const int NA = B_DIM * D_DIM / 8;        // 1,572,864
    const int NW = 4 * HID * D_DIM / 8;      // 3,145,728
    const int total = NA + NW;
    for (int idx = blockIdx.x * blockDim.x + threadIdx.x; idx < total;
         idx += gridDim.x * blockDim.x) {
        const float* src;
        unsigned short* dst;
        if (idx < NA) {
            const int C8 = D_DIM / 8;        // 384
            int b = idx / C8, c8 = idx - b * C8;
            src = (c8 < IN_SZ / 8) ? x + (size_t)b * IN_SZ + c8 * 8
                                   : h + (size_t)b * HID + (c8 - IN_SZ / 8) * 8;
            dst = Abf + (size_t)idx * 8;
        } else {
            int wi = idx - NA;
            const int PG = HID * D_DIM / 8;  // 786,432 per gate
            int g = wi / PG, r = wi - g * PG;
            const float* W = (g == 0) ? W0 : (g == 1) ? W1 : (g == 2) ? W2 : W3;
            src = W + (size_t)r * 8;
            dst = Wbf + (size_t)wi * 8;
        }
        float4 v0 = ((const float4*)src)[0];
        float4 v1 = ((const float4*)src)[1];
        short8 o;
        o[0] = (short)f2bf(v0.x); o[1] = (short)f2bf(v0.y);
        o[2] = (short)f2bf(v0.z); o[3] = (short)f2bf(v0.w);
        o[4] = (short)f2bf(v1.x); o[5] = (short)f2bf(v1.y);
        o[6] = (short)f2bf(v1.z); o[7] = (short)f2bf(v1.w);
        *(short8*)dst = o;
    }
}

// ---------- MFMA cluster: 16 MFMAs = m-frags [IB..IB+4) x all 4 n-frags ----------
template <int IB>
__device__ __forceinline__ void mfma16(f32x4 (&acc)[8][4], const short8 (&a)[4],
                                       const short8 (&b)[4]) {
#pragma unroll
    for (int i = 0; i < 4; ++i)
#pragma unroll
        for (int j = 0; j < 4; ++j)
            acc[IB + i][j] = __builtin_amdgcn_mfma_f32_16x16x32_bf16(
                a[i], b[j], acc[IB + i][j], 0, 0, 0);
}

// ---- phase-pair Pj: read region KS (12 ds_read_b128), stage region SKS of tile
// stElem (4 gload_lds), 32 MFMA, counted vmcnt(8), barrier.
// Ledger (steady state, 4 loads/region): at each pair-end, outstanding = 3 regions
// (12 loads); vmcnt(8) retires exactly the region read NEXT pair -> cross-wave RAW
// closed by the barrier; 8 loads (2 newest regions) stay in flight -> never drains.
// WAR: stage of a region is issued the pair AFTER its readers' pair-end barrier
// (all ds_reads lgkm-retired before each wave's barrier).
template <int KS, int SKS>
__device__ __forceinline__ void pair_body(
    f32x4 (&acc)[8][4], char* sm, int aOff, int bOff, int wchunk,
    const unsigned short* sA, const unsigned short* sB0, const unsigned short* sB1,
    int stElem) {
    const char* reg = sm + KS * 16384;
    short8 a0[4], bb[4], a1[4];
#pragma unroll
    for (int i = 0; i < 4; ++i)
        a0[i] = *(const short8*)(reg + aOff + i * 1024);
#pragma unroll
    for (int j = 0; j < 4; ++j)
        bb[j] = *(const short8*)(reg + bOff + j * 1024);
#pragma unroll
    for (int i = 0; i < 4; ++i)
        a1[i] = *(const short8*)(reg + aOff + (4 + i) * 1024);
    char* dA = sm + SKS * 16384 + wchunk;
    char* dB = dA + 65536;
    async_load16(sA + stElem,         dA);
    async_load16(sA + 49152 + stElem, dA + 1024);
    async_load16(sB0 + stElem,        dB);
    async_load16(sB1 + stElem,        dB + 1024);
    __builtin_amdgcn_sched_barrier(0);
    __builtin_amdgcn_s_setprio(1);
    mfma16<0>(acc, a0, bb);    // compiler: counted lgkm leaves a1 in flight
    mfma16<4>(acc, a1, bb);
    __builtin_amdgcn_s_setprio(0);
    asm volatile("s_waitcnt vmcnt(8)" ::: "memory");
    __builtin_amdgcn_s_barrier();
    asm volatile("" ::: "memory");
}

// ---- fused gate-GEMM + LSTM epilogue, 256x(64h x 4gates), BK=128, 8 waves ----
// col = h_hi*64 + gate*16 + h_lo -> all 4 gates of an (m,h) share a lane.
// LDS: ONE 128-KB buffer, 4 k-slice regions: A[ks]: ks*16K (256 rows x 32 bf16,
// 64-B rows), B[ks]: 64K + ks*16K. Swizzle: slot ^= row&3 (16-B slots, 4/row) on
// BOTH the pre-swizzled staging source and the ds_read offset (8-lane/4-bank-group
// uniform -> structural-minimum LDS service).
__global__ __launch_bounds__(512, 2)
void lstm_gemm(const unsigned short* __restrict__ Abf,   // [B][D] bf16
               const unsigned short* __restrict__ Wbf,   // [4H][D] bf16
               const float* __restrict__ b_i, const float* __restrict__ b_f,
               const float* __restrict__ b_c, const float* __restrict__ b_o,
               const float* __restrict__ c_prev,
               float* __restrict__ h_out, float* __restrict__ c_out) {
    extern __shared__ char sm[];   // 131072 B

    const int tid  = threadIdx.x;
    const int lane = tid & 63;
    const int wave = tid >> 6;          // 0..7
    const int wm   = wave >> 2;         // 0..1
    const int wn   = wave & 3;          // 0..3
    const int l16  = lane & 15;
    const int quad = lane >> 4;

    const int m0 = blockIdx.x * BM;
    const int h0 = blockIdx.y * BN;

    // ---- staging addressing: instr (wave,i) covers rows wave*32+i*16 .. +16 ----
    const int srow = lane >> 2;                 // 0..15 row within 16-row chunk
    const int sl   = (lane & 3) ^ (srow & 3);   // pre-swizzled source slot (involution)
    const unsigned short* sA = Abf + (size_t)(m0 + wave * 32 + srow) * D_DIM + sl * 8;
    // B tile row rt -> W row: gate=(rt>>4)&3, h = h0 + (rt>>6)*16 + (rt&15)
    const int rt0 = wave * 32 + srow;
    const int rt1 = rt0 + 16;
    const int g0  = ((rt0 >> 4) & 3) * HID + h0 + (rt0 >> 6) * 16 + (rt0 & 15);
    const int g1  = ((rt1 >> 4) & 3) * HID + h0 + (rt1 >> 6) * 16 + (rt1 & 15);
    const unsigned short* sB0 = Wbf + (size_t)g0 * D_DIM + sl * 8;
    const unsigned short* sB1 = Wbf + (size_t)g1 * D_DIM + sl * 8;
    const int wchunk = wave * 2048;             // 32 rows x 64 B per wave

    // ---- ds_read addressing: byte = ks*16K + row*64 + (quad^(row&3))*16 ----
    const int slotSw = (quad ^ (l16 & 3)) * 16;
    const int aOff = (wm * 128 + l16) * 64 + slotSw;            // + i*1024 per m-frag
    const int bOff = 65536 + (wn * 64 + l16) * 64 + slotSw;     // + j*1024 per n-frag

    f32x4 acc[8][4] = {};

    // ---- prologue: stage regions ks0,ks1,ks2 of tile 0 (oldest-first) ----
#pragma unroll
    for (int s = 0; s < 3; ++s) {
        char* dA = sm + s * 16384 + wchunk;
        char* dB = dA + 65536;
        const int e = s * 32;
        async_load16(sA + e,         dA);
        async_load16(sA + 49152 + e, dA + 1024);
        async_load16(sB0 + e,        dB);
        async_load16(sB1 + e,        dB + 1024);
    }
    asm volatile("s_waitcnt vmcnt(8)" ::: "memory");   // ks0 landed; ks1,ks2 in flight
    __builtin_amdgcn_s_barrier();
    asm volatile("" ::: "memory");

    for (int kt = 0; kt < NT2; ++kt) {
        const int kn = (kt < NT2 - 1) ? kt + 1 : kt;   // last iter: restage (raceless)
        pair_body<0, 3>(acc, sm, aOff, bOff, wchunk, sA, sB0, sB1, kt * 128 + 96);
        pair_body<1, 0>(acc, sm, aOff, bOff, wchunk, sA, sB0, sB1, kn * 128 + 0);
        pair_body<2, 1>(acc, sm, aOff, bOff, wchunk, sA, sB0, sB1, kn * 128 + 32);
        pair_body<3, 2>(acc, sm, aOff, bOff, wchunk, sA, sB0, sB1, kn * 128 + 64);
    }
    asm volatile("s_waitcnt vmcnt(0)" ::: "memory");

    // ---- epilogue: C layout col = lane&15, row = quad*4 + reg ----
    const int h = h0 + wn * 16 + l16;
    const float biv = b_i[h], bfv = b_f[h], bcv = b_c[h], bov = b_o[h];
    const int mb = m0 + wm * 128 + quad * 4;
#pragma unroll
    for (int i = 0; i < 8; ++i) {
#pragma unroll
        for (int r = 0; r < 4; ++r) {
            const int m = mb + i * 16 + r;
            const size_t off = (size_t)m * HID + h;
            const float gi = acc[i][0][r] + biv;
            const float gf = acc[i][1][r] + bfv;
            const float gc = acc[i][2][r] + bcv;
            const float go = acc[i][3][r] + bov;
            const float it = sigm(gi), ft = sigm(gf);
            const float gt = tanh_f(gc), ot = sigm(go);
            const float cc = ft * c_prev[off] + it * gt;
            h_out[off] = ot * tanh_f(cc);
            c_out[off] = cc;
        }
    }
}

extern "C" void kernel_launch(void* const* d_in, const int* in_sizes, int n_in,
                              void* d_out, int out_size, void* d_ws, size_t ws_size,
                              hipStream_t stream) {
    const float* x_t    = (const float*)d_in[0];
    const float* h_prev = (const float*)d_in[1];
    const float* c_prev = (const float*)d_in[2];
    const float* W_i = (const float*)d_in[3];
    const float* b_i = (const float*)d_in[4];
    const float* W_f = (const float*)d_in[5];
    const float* b_f = (const float*)d_in[6];
    const float* W_c = (const float*)d_in[7];
    const float* b_c = (const float*)d_in[8];
    const float* W_o = (const float*)d_in[9];
    const float* b_o = (const float*)d_in[10];
    float* out = (float*)d_out;

    unsigned short* Abf = (unsigned short*)d_ws;                       // 25,165,824 B
    unsigned short* Wbf = (unsigned short*)((char*)d_ws + (size_t)B_DIM * D_DIM * 2);
    // total ws use: 75,497,472 B

    static bool s_attr = false;
    if (!s_attr) {
        (void)hipFuncSetAttribute((const void*)lstm_gemm,
                                  hipFuncAttributeMaxDynamicSharedMemorySize, 131072);
        s_attr = true;
    }

    convert_all<<<2048, 256, 0, stream>>>(x_t, h_prev, W_i, W_f, W_c, W_o, Abf, Wbf);

    dim3 grid(B_DIM / BM, HID / BN);   // 16 x 32
    lstm_gemm<<<grid, 512, 131072, stream>>>(Abf, Wbf, b_i, b_f, b_c, b_o, c_prev,
                                             out, out + (size_t)B_DIM * HID);
}